// Round 3
// baseline (254.835 us; speedup 1.0000x reference)
//
#include <hip/hip_runtime.h>

#define NPOS 4096      // H*W
#define NCH  256       // channels
#define HD   32        // head dim
#define KB   64        // keys per attention step

typedef float f32x4 __attribute__((ext_vector_type(4)));
typedef short s16x8 __attribute__((ext_vector_type(8)));
typedef uint  u32x4 __attribute__((ext_vector_type(4)));

static __device__ __forceinline__ s16x8 load8(const ushort* p) {
    return *(const s16x8*)p;
}
static __device__ __forceinline__ ushort bfbits(float x) {
    __bf16 b = (__bf16)x;
    return __builtin_bit_cast(unsigned short, b);
}
static __device__ __forceinline__ uint pk2(float a, float b) {
    return (uint)bfbits(a) | ((uint)bfbits(b) << 16);
}
static __device__ __forceinline__ f32x4 max4(f32x4 a, f32x4 b) {
    f32x4 r;
    r[0] = fmaxf(a[0], b[0]); r[1] = fmaxf(a[1], b[1]);
    r[2] = fmaxf(a[2], b[2]); r[3] = fmaxf(a[3], b[3]);
    return r;
}

// ---------------- projections (f32 math, exact) ----------------

// Q or K: 16 out-channels/block, write bf16 [head][n][32], scale folded in.
__global__ __launch_bounds__(256) void proj_nd16_kernel(
    const float* __restrict__ X, const float* __restrict__ W,
    ushort* __restrict__ Y, float scale)
{
    __shared__ float w_lds[16 * NCH];
    const int n  = blockIdx.x * 256 + threadIdx.x;
    const int o0 = blockIdx.y * 16;
    for (int i = threadIdx.x; i < 16 * NCH; i += 256)
        w_lds[i] = W[o0 * NCH + i];
    __syncthreads();

    float acc[16];
#pragma unroll
    for (int j = 0; j < 16; ++j) acc[j] = 0.f;
#pragma unroll 4
    for (int c = 0; c < NCH; ++c) {
        float xv = X[c * NPOS + n];
#pragma unroll
        for (int j = 0; j < 16; ++j)
            acc[j] = fmaf(w_lds[j * NCH + c], xv, acc[j]);
    }
    const int head = o0 >> 5, d0 = o0 & 31;
    ushort* base = Y + head * (NPOS * HD) + n * HD + d0;
    uint w[8];
#pragma unroll
    for (int i = 0; i < 8; ++i)
        w[i] = pk2(acc[2 * i] * scale, acc[2 * i + 1] * scale);
    *(u32x4*)(base)     = (u32x4){w[0], w[1], w[2], w[3]};
    *(u32x4*)(base + 8) = (u32x4){w[4], w[5], w[6], w[7]};
}

// K+V fused: both read x2; 16 K-channels + 16 V-channels per block.
// K -> bf16 [head][n][32]; V -> bf16 [head*32+d][n].
__global__ __launch_bounds__(256) void proj_kv_kernel(
    const float* __restrict__ X, const float* __restrict__ Wk,
    const float* __restrict__ Wv, ushort* __restrict__ Yk,
    ushort* __restrict__ Yv)
{
    __shared__ float w_lds[32 * NCH];   // 32 KB: [0..4095]=Wk rows, [4096..]=Wv
    const int n  = blockIdx.x * 256 + threadIdx.x;
    const int o0 = blockIdx.y * 16;
    for (int i = threadIdx.x; i < 16 * NCH; i += 256) {
        w_lds[i]            = Wk[o0 * NCH + i];
        w_lds[16 * NCH + i] = Wv[o0 * NCH + i];
    }
    __syncthreads();

    float acck[16], accv[16];
#pragma unroll
    for (int j = 0; j < 16; ++j) { acck[j] = 0.f; accv[j] = 0.f; }
#pragma unroll 4
    for (int c = 0; c < NCH; ++c) {
        float xv = X[c * NPOS + n];
#pragma unroll
        for (int j = 0; j < 16; ++j) {
            acck[j] = fmaf(w_lds[j * NCH + c], xv, acck[j]);
            accv[j] = fmaf(w_lds[16 * NCH + j * NCH + c], xv, accv[j]);
        }
    }
    const int head = o0 >> 5, d0 = o0 & 31;
    ushort* base = Yk + head * (NPOS * HD) + n * HD + d0;
    uint w[8];
#pragma unroll
    for (int i = 0; i < 8; ++i)
        w[i] = pk2(acck[2 * i], acck[2 * i + 1]);
    *(u32x4*)(base)     = (u32x4){w[0], w[1], w[2], w[3]};
    *(u32x4*)(base + 8) = (u32x4){w[4], w[5], w[6], w[7]};
#pragma unroll
    for (int j = 0; j < 16; ++j)
        Yv[(o0 + j) * NPOS + n] = bfbits(accv[j]);
}

// Output projection: f32 in, f32 out, + bias. 16 out-channels/block.
__global__ __launch_bounds__(256) void proj_f32_kernel(
    const float* __restrict__ X, const float* __restrict__ W,
    const float* __restrict__ bias, float* __restrict__ Y)
{
    __shared__ float w_lds[16 * NCH];
    const int n  = blockIdx.x * 256 + threadIdx.x;
    const int o0 = blockIdx.y * 16;
    for (int i = threadIdx.x; i < 16 * NCH; i += 256)
        w_lds[i] = W[o0 * NCH + i];
    __syncthreads();

    float acc[16];
#pragma unroll
    for (int j = 0; j < 16; ++j) acc[j] = 0.f;
#pragma unroll 4
    for (int c = 0; c < NCH; ++c) {
        float xv = X[c * NPOS + n];
#pragma unroll
        for (int j = 0; j < 16; ++j)
            acc[j] = fmaf(w_lds[j * NCH + c], xv, acc[j]);
    }
#pragma unroll
    for (int j = 0; j < 16; ++j)
        Y[(o0 + j) * NPOS + n] = acc[j] + bias[o0 + j];
}

// ---------------- MFMA flash attention ----------------
// 512 blocks (h = bid&7), 4 waves, 16 queries per wave -> 2048 waves
// = 2 waves/SIMD so softmax VALU overlaps the other wave's MFMA.
__global__ __launch_bounds__(256) void attn_mfma_kernel(
    const ushort* __restrict__ Qt,   // [8][4096][32] bf16, pre-scaled s*log2e
    const ushort* __restrict__ Kt,   // [8][4096][32] bf16
    const ushort* __restrict__ Vt,   // [8][32][4096] bf16
    float* __restrict__ F)           // [256][4096] f32
{
    __shared__ ushort pt_all[4][16 * KB];
    const int bid  = blockIdx.x;
    const int h    = bid & 7;
    const int qblk = bid >> 3;      // 0..63
    const int wid  = threadIdx.x >> 6;
    const int lane = threadIdx.x & 63;
    const int lq   = lane & 15;     // fragment column (query)
    const int grp  = lane >> 4;     // 0..3
    const int q0   = qblk * 64 + wid * 16;

    ushort* pt = pt_all[wid];
    const int hq = h * (NPOS * HD);

    const s16x8 qf = load8(Qt + hq + (q0 + lq) * HD + grp * 8);
    const ushort* kbase = Kt + hq + lq * HD + grp * 8;
    const ushort* vbase = Vt + h * (HD * NPOS) + lq * NPOS + grp * 8;

    f32x4 oacc[2];
    oacc[0] = (f32x4){0.f, 0.f, 0.f, 0.f};
    oacc[1] = (f32x4){0.f, 0.f, 0.f, 0.f};
    float m_run = -INFINITY, l_run = 0.f;

    s16x8 kf[4];
#pragma unroll
    for (int t = 0; t < 4; ++t) kf[t] = load8(kbase + t * 16 * HD);

    for (int m0 = 0; m0 < NPOS; m0 += KB) {
        // --- QK^T: S^T tiles (rows = m, cols = q) ---
        f32x4 s[4];
#pragma unroll
        for (int t = 0; t < 4; ++t)
            s[t] = __builtin_amdgcn_mfma_f32_16x16x32_bf16(
                kf[t], qf, (f32x4){0.f, 0.f, 0.f, 0.f}, 0, 0, 0);

        // prefetch next K tile + this step's V fragments
        const int mn = (m0 + KB) & (NPOS - 1);
        s16x8 kn[4];
#pragma unroll
        for (int t = 0; t < 4; ++t) kn[t] = load8(kbase + (mn + t * 16) * HD);
        s16x8 vf[2][2];
#pragma unroll
        for (int ks = 0; ks < 2; ++ks)
#pragma unroll
            for (int dt = 0; dt < 2; ++dt)
                vf[ks][dt] = load8(vbase + dt * 16 * NPOS + m0 + ks * 32);

        // --- online softmax (exp2 domain), defer-max THR=8 ---
        f32x4 mv = max4(max4(s[0], s[1]), max4(s[2], s[3]));
        float mt = fmaxf(fmaxf(mv[0], mv[1]), fmaxf(mv[2], mv[3]));
        mt = fmaxf(mt, __shfl_xor(mt, 16));
        mt = fmaxf(mt, __shfl_xor(mt, 32));
        if (__any(mt > m_run + 8.f)) {
            const float mnew  = fmaxf(m_run, mt);
            const float alpha = __builtin_amdgcn_exp2f(m_run - mnew);
            m_run = mnew;
            l_run *= alpha;
            oacc[0] *= alpha;
            oacc[1] *= alpha;
        }
        float ls = 0.f;
#pragma unroll
        for (int t = 0; t < 4; ++t) {
            const float p0 = __builtin_amdgcn_exp2f(s[t][0] - m_run);
            const float p1 = __builtin_amdgcn_exp2f(s[t][1] - m_run);
            const float p2 = __builtin_amdgcn_exp2f(s[t][2] - m_run);
            const float p3 = __builtin_amdgcn_exp2f(s[t][3] - m_run);
            ls += (p0 + p1) + (p2 + p3);
            const int mrow = t * 16 + grp * 4;
            const int hw = lq * KB + (((mrow >> 3) ^ (lq & 7)) << 3) + (mrow & 7);
            *(uint*)(pt + hw)     = pk2(p0, p1);
            *(uint*)(pt + hw + 2) = pk2(p2, p3);
        }
        l_run += ls;

        // --- PV: O^T (rows = d, cols = q), contract over m ---
#pragma unroll
        for (int ks = 0; ks < 2; ++ks) {
            const int mcol = ks * 32 + grp * 8;
            const int hw = lq * KB + (((mcol >> 3) ^ (lq & 7)) << 3);
            const s16x8 pf = *(const s16x8*)(pt + hw);
            oacc[0] = __builtin_amdgcn_mfma_f32_16x16x32_bf16(
                vf[ks][0], pf, oacc[0], 0, 0, 0);
            oacc[1] = __builtin_amdgcn_mfma_f32_16x16x32_bf16(
                vf[ks][1], pf, oacc[1], 0, 0, 0);
        }

#pragma unroll
        for (int t = 0; t < 4; ++t) kf[t] = kn[t];
    }

    // --- normalize + write fused (f32, [c][n]) ---
    float l = l_run;
    l += __shfl_xor(l, 16);
    l += __shfl_xor(l, 32);
    const float inv = 1.f / l;
    const int n = q0 + lq;
#pragma unroll
    for (int dt = 0; dt < 2; ++dt)
#pragma unroll
        for (int r = 0; r < 4; ++r)
            F[(h * HD + dt * 16 + grp * 4 + r) * NPOS + n] = oacc[dt][r] * inv;
}

extern "C" void kernel_launch(void* const* d_in, const int* in_sizes, int n_in,
                              void* d_out, int out_size, void* d_ws, size_t ws_size,
                              hipStream_t stream) {
    const float* x1 = (const float*)d_in[0];
    const float* x2 = (const float*)d_in[1];
    const float* Wq = (const float*)d_in[2];
    const float* Wk = (const float*)d_in[3];
    const float* Wv = (const float*)d_in[4];
    const float* Wp = (const float*)d_in[5];
    const float* bp = (const float*)d_in[6];
    float* out = (float*)d_out;

    ushort* qt = (ushort*)d_ws;              // 2 MB bf16 [8][4096][32]
    ushort* kt = qt + NPOS * NCH;            // 2 MB
    ushort* vt = kt + NPOS * NCH;            // 2 MB [8][32][4096]
    float*  fu = (float*)(vt + NPOS * NCH);  // 4 MB f32 [256][4096]

    const float qscale = (float)(0.17677669529663687 * 1.4426950408889634);

    dim3 pgrid(NPOS / 256, NCH / 16);
    proj_nd16_kernel<<<pgrid, 256, 0, stream>>>(x1, Wq, qt, qscale);
    proj_kv_kernel<<<pgrid, 256, 0, stream>>>(x2, Wk, Wv, kt, vt);

    attn_mfma_kernel<<<512, 256, 0, stream>>>(qt, kt, vt, fu);

    proj_f32_kernel<<<pgrid, 256, 0, stream>>>(fu, Wp, bp, out);
}

// Round 4
// 143.554 us; speedup vs baseline: 1.7752x; 1.7752x over previous
//
#include <hip/hip_runtime.h>

#define NPOS 4096      // H*W
#define NCH  256       // channels
#define HD   32        // head dim
#define KB   64        // keys per attention step
#define SPLIT_KEYS 2048

typedef float f32x4 __attribute__((ext_vector_type(4)));
typedef short s16x8 __attribute__((ext_vector_type(8)));
typedef uint  u32x4 __attribute__((ext_vector_type(4)));

static __device__ __forceinline__ s16x8 load8(const ushort* p) {
    return *(const s16x8*)p;
}
static __device__ __forceinline__ ushort bfbits(float x) {
    __bf16 b = (__bf16)x;
    return __builtin_bit_cast(unsigned short, b);
}
static __device__ __forceinline__ uint pk2(float a, float b) {
    return (uint)bfbits(a) | ((uint)bfbits(b) << 16);
}
static __device__ __forceinline__ f32x4 max4(f32x4 a, f32x4 b) {
    f32x4 r;
    r[0] = fmaxf(a[0], b[0]); r[1] = fmaxf(a[1], b[1]);
    r[2] = fmaxf(a[2], b[2]); r[3] = fmaxf(a[3], b[3]);
    return r;
}

// ---------------- projections (f32 math, exact) ----------------

// Q: 8 out-channels/block (512 blocks), bf16 [head][n][32], scale folded.
__global__ __launch_bounds__(256) void proj_q_kernel(
    const float* __restrict__ X, const float* __restrict__ W,
    ushort* __restrict__ Y, float scale)
{
    __shared__ float w_lds[8 * NCH];
    const int n  = blockIdx.x * 256 + threadIdx.x;
    const int o0 = blockIdx.y * 8;
    for (int i = threadIdx.x; i < 8 * NCH; i += 256)
        w_lds[i] = W[o0 * NCH + i];
    __syncthreads();

    float acc[8];
#pragma unroll
    for (int j = 0; j < 8; ++j) acc[j] = 0.f;
#pragma unroll 4
    for (int c = 0; c < NCH; ++c) {
        float xv = X[c * NPOS + n];
#pragma unroll
        for (int j = 0; j < 8; ++j)
            acc[j] = fmaf(w_lds[j * NCH + c], xv, acc[j]);
    }
    const int head = o0 >> 5, d0 = o0 & 31;
    ushort* base = Y + head * (NPOS * HD) + n * HD + d0;
    *(u32x4*)base = (u32x4){pk2(acc[0] * scale, acc[1] * scale),
                            pk2(acc[2] * scale, acc[3] * scale),
                            pk2(acc[4] * scale, acc[5] * scale),
                            pk2(acc[6] * scale, acc[7] * scale)};
}

// K+V fused (both read x2): 8 K-ch + 8 V-ch per block (512 blocks).
// K -> bf16 [head][n][32]; V -> bf16 [head*32+d][n].
__global__ __launch_bounds__(256) void proj_kv_kernel(
    const float* __restrict__ X, const float* __restrict__ Wk,
    const float* __restrict__ Wv, ushort* __restrict__ Yk,
    ushort* __restrict__ Yv)
{
    __shared__ float w_lds[16 * NCH];
    const int n  = blockIdx.x * 256 + threadIdx.x;
    const int o0 = blockIdx.y * 8;
    for (int i = threadIdx.x; i < 8 * NCH; i += 256) {
        w_lds[i]           = Wk[o0 * NCH + i];
        w_lds[8 * NCH + i] = Wv[o0 * NCH + i];
    }
    __syncthreads();

    float acck[8], accv[8];
#pragma unroll
    for (int j = 0; j < 8; ++j) { acck[j] = 0.f; accv[j] = 0.f; }
#pragma unroll 4
    for (int c = 0; c < NCH; ++c) {
        float xv = X[c * NPOS + n];
#pragma unroll
        for (int j = 0; j < 8; ++j) {
            acck[j] = fmaf(w_lds[j * NCH + c], xv, acck[j]);
            accv[j] = fmaf(w_lds[8 * NCH + j * NCH + c], xv, accv[j]);
        }
    }
    const int head = o0 >> 5, d0 = o0 & 31;
    ushort* base = Yk + head * (NPOS * HD) + n * HD + d0;
    *(u32x4*)base = (u32x4){pk2(acck[0], acck[1]), pk2(acck[2], acck[3]),
                            pk2(acck[4], acck[5]), pk2(acck[6], acck[7])};
#pragma unroll
    for (int j = 0; j < 8; ++j)
        Yv[(o0 + j) * NPOS + n] = bfbits(accv[j]);
}

// Output projection with fused split-K combine: reads unnormalized partials
// Op[2][256][4096] + Ml[2][8][2][4096], produces out = Wp @ fused + bias.
__global__ __launch_bounds__(256) void proj_out_kernel(
    const float* __restrict__ Op, const float* __restrict__ Ml,
    const float* __restrict__ W, const float* __restrict__ bias,
    float* __restrict__ Y)
{
    __shared__ float w_lds[8 * NCH];
    const int n  = blockIdx.x * 256 + threadIdx.x;
    const int o0 = blockIdx.y * 8;
    for (int i = threadIdx.x; i < 8 * NCH; i += 256)
        w_lds[i] = W[o0 * NCH + i];
    __syncthreads();

    const float* Op0 = Op;
    const float* Op1 = Op + NCH * NPOS;

    float acc[8];
#pragma unroll
    for (int j = 0; j < 8; ++j) acc[j] = 0.f;

    for (int h = 0; h < 8; ++h) {
        const float m0 = Ml[(h * 2) * NPOS + n];
        const float l0 = Ml[(h * 2 + 1) * NPOS + n];
        const float m1 = Ml[((8 + h) * 2) * NPOS + n];
        const float l1 = Ml[((8 + h) * 2 + 1) * NPOS + n];
        const float M  = fmaxf(m0, m1);
        const float w0 = __builtin_amdgcn_exp2f(m0 - M);
        const float w1 = __builtin_amdgcn_exp2f(m1 - M);
        const float inv = 1.f / fmaf(l0, w0, l1 * w1);
        const float a0 = w0 * inv, a1 = w1 * inv;
#pragma unroll 4
        for (int cc = 0; cc < 32; ++cc) {
            const int c = h * 32 + cc;
            const float xv = fmaf(Op0[c * NPOS + n], a0, Op1[c * NPOS + n] * a1);
#pragma unroll
            for (int j = 0; j < 8; ++j)
                acc[j] = fmaf(w_lds[j * NCH + c], xv, acc[j]);
        }
    }
#pragma unroll
    for (int j = 0; j < 8; ++j)
        Y[(o0 + j) * NPOS + n] = acc[j] + bias[o0 + j];
}

// ---------------- MFMA flash attention, split-K over 2 ----------------
// 512 blocks: s = bid>>8 (key split), h = bid&7, qblk = (bid&255)>>3.
// 4 waves x 32 queries. Writes unnormalized O' and (m,l) per split.
__global__ __launch_bounds__(256) void attn_mfma_kernel(
    const ushort* __restrict__ Qt,   // [8][4096][32] bf16, pre-scaled s*log2e
    const ushort* __restrict__ Kt,   // [8][4096][32] bf16
    const ushort* __restrict__ Vt,   // [8][32][4096] bf16
    float* __restrict__ Op,          // [2][256][4096] f32 unnormalized
    float* __restrict__ Ml)          // [2][8][2][4096] f32 (m, l)
{
    __shared__ ushort pt_all[4][32 * KB];
    const int bid  = blockIdx.x;
    const int s    = bid >> 8;
    const int h    = bid & 7;
    const int qblk = (bid & 255) >> 3;   // 0..31
    const int wid  = threadIdx.x >> 6;
    const int lane = threadIdx.x & 63;
    const int lq   = lane & 15;
    const int grp  = lane >> 4;
    const int q0   = qblk * 128 + wid * 32;
    const int k0   = s * SPLIT_KEYS;

    ushort* pt = pt_all[wid];
    const int hq = h * (NPOS * HD);

    s16x8 qf[2];
#pragma unroll
    for (int qt = 0; qt < 2; ++qt)
        qf[qt] = load8(Qt + hq + (q0 + qt * 16 + lq) * HD + grp * 8);

    const ushort* kbase = Kt + hq + lq * HD + grp * 8;
    const ushort* vbase = Vt + h * (HD * NPOS) + lq * NPOS + grp * 8;

    f32x4 oacc[2][2];
#pragma unroll
    for (int qt = 0; qt < 2; ++qt)
#pragma unroll
        for (int dt = 0; dt < 2; ++dt)
            oacc[qt][dt] = (f32x4){0.f, 0.f, 0.f, 0.f};
    float m_run[2] = {-INFINITY, -INFINITY};
    float l_run[2] = {0.f, 0.f};

    s16x8 kf[4];
#pragma unroll
    for (int t = 0; t < 4; ++t) kf[t] = load8(kbase + (k0 + t * 16) * HD);

    for (int m0 = k0; m0 < k0 + SPLIT_KEYS; m0 += KB) {
        // --- QK^T: S^T tiles (rows = m, cols = q) ---
        f32x4 s_[2][4];
#pragma unroll
        for (int t = 0; t < 4; ++t)
#pragma unroll
            for (int qt = 0; qt < 2; ++qt)
                s_[qt][t] = __builtin_amdgcn_mfma_f32_16x16x32_bf16(
                    kf[t], qf[qt], (f32x4){0.f, 0.f, 0.f, 0.f}, 0, 0, 0);

        // prefetch next K tile + this step's V fragments
        const int mn = k0 + ((m0 - k0 + KB) & (SPLIT_KEYS - 1));
        s16x8 kn[4];
#pragma unroll
        for (int t = 0; t < 4; ++t) kn[t] = load8(kbase + (mn + t * 16) * HD);
        s16x8 vf[2][2];
#pragma unroll
        for (int ks = 0; ks < 2; ++ks)
#pragma unroll
            for (int dt = 0; dt < 2; ++dt)
                vf[ks][dt] = load8(vbase + dt * 16 * NPOS + m0 + ks * 32);

        // --- online softmax (exp2 domain), defer-max THR=8 ---
#pragma unroll
        for (int qt = 0; qt < 2; ++qt) {
            f32x4 mv = max4(max4(s_[qt][0], s_[qt][1]), max4(s_[qt][2], s_[qt][3]));
            float mt = fmaxf(fmaxf(mv[0], mv[1]), fmaxf(mv[2], mv[3]));
            mt = fmaxf(mt, __shfl_xor(mt, 16));
            mt = fmaxf(mt, __shfl_xor(mt, 32));
            if (__any(mt > m_run[qt] + 8.f)) {
                const float mnew  = fmaxf(m_run[qt], mt);
                const float alpha = __builtin_amdgcn_exp2f(m_run[qt] - mnew);
                m_run[qt] = mnew;
                l_run[qt] *= alpha;
                oacc[qt][0] *= alpha;
                oacc[qt][1] *= alpha;
            }
            float ls = 0.f;
#pragma unroll
            for (int t = 0; t < 4; ++t) {
                const float p0 = __builtin_amdgcn_exp2f(s_[qt][t][0] - m_run[qt]);
                const float p1 = __builtin_amdgcn_exp2f(s_[qt][t][1] - m_run[qt]);
                const float p2 = __builtin_amdgcn_exp2f(s_[qt][t][2] - m_run[qt]);
                const float p3 = __builtin_amdgcn_exp2f(s_[qt][t][3] - m_run[qt]);
                ls += (p0 + p1) + (p2 + p3);
                const int mrow = t * 16 + grp * 4;
                const int hw = (qt * 16 + lq) * KB +
                               (((mrow >> 3) ^ (lq & 7)) << 3) + (mrow & 7);
                *(uint*)(pt + hw)     = pk2(p0, p1);
                *(uint*)(pt + hw + 2) = pk2(p2, p3);
            }
            l_run[qt] += ls;
        }

        // --- PV: O^T (rows = d, cols = q), contract over m ---
#pragma unroll
        for (int ks = 0; ks < 2; ++ks)
#pragma unroll
            for (int qt = 0; qt < 2; ++qt) {
                const int hw = (qt * 16 + lq) * KB +
                               ((((ks * 32 + grp * 8) >> 3) ^ (lq & 7)) << 3);
                const s16x8 pf = *(const s16x8*)(pt + hw);
                oacc[qt][0] = __builtin_amdgcn_mfma_f32_16x16x32_bf16(
                    vf[ks][0], pf, oacc[qt][0], 0, 0, 0);
                oacc[qt][1] = __builtin_amdgcn_mfma_f32_16x16x32_bf16(
                    vf[ks][1], pf, oacc[qt][1], 0, 0, 0);
            }

#pragma unroll
        for (int t = 0; t < 4; ++t) kf[t] = kn[t];
    }

    // --- write unnormalized partials + (m, l) ---
    float* Ops = Op + s * (NCH * NPOS);
#pragma unroll
    for (int qt = 0; qt < 2; ++qt) {
        float l = l_run[qt];
        l += __shfl_xor(l, 16);
        l += __shfl_xor(l, 32);
        const int n = q0 + qt * 16 + lq;
#pragma unroll
        for (int dt = 0; dt < 2; ++dt)
#pragma unroll
            for (int r = 0; r < 4; ++r)
                Ops[(h * HD + dt * 16 + grp * 4 + r) * NPOS + n] = oacc[qt][dt][r];
        if (lane < 16) {
            Ml[((s * 8 + h) * 2) * NPOS + n]     = m_run[qt];
            Ml[((s * 8 + h) * 2 + 1) * NPOS + n] = l;
        }
    }
}

extern "C" void kernel_launch(void* const* d_in, const int* in_sizes, int n_in,
                              void* d_out, int out_size, void* d_ws, size_t ws_size,
                              hipStream_t stream) {
    const float* x1 = (const float*)d_in[0];
    const float* x2 = (const float*)d_in[1];
    const float* Wq = (const float*)d_in[2];
    const float* Wk = (const float*)d_in[3];
    const float* Wv = (const float*)d_in[4];
    const float* Wp = (const float*)d_in[5];
    const float* bp = (const float*)d_in[6];
    float* out = (float*)d_out;

    ushort* qt = (ushort*)d_ws;              // 2 MB bf16 [8][4096][32]
    ushort* kt = qt + NPOS * NCH;            // 2 MB
    ushort* vt = kt + NPOS * NCH;            // 2 MB [8][32][4096]
    float*  Op = (float*)(vt + NPOS * NCH);  // 8 MB f32 [2][256][4096]
    float*  Ml = Op + 2 * NCH * NPOS;        // 512 KB f32 [2][8][2][4096]

    const float qscale = (float)(0.17677669529663687 * 1.4426950408889634);

    dim3 pgrid(NPOS / 256, NCH / 8);
    proj_q_kernel<<<pgrid, 256, 0, stream>>>(x1, Wq, qt, qscale);
    proj_kv_kernel<<<pgrid, 256, 0, stream>>>(x2, Wk, Wv, kt, vt);

    attn_mfma_kernel<<<512, 256, 0, stream>>>(qt, kt, vt, Op, Ml);

    proj_out_kernel<<<pgrid, 256, 0, stream>>>(Op, Ml, Wp, bp, out);
}

// Round 5
// 110.273 us; speedup vs baseline: 2.3110x; 1.3018x over previous
//
#include <hip/hip_runtime.h>

#define NPOS 4096      // H*W
#define NCH  256       // channels
#define HD   32        // head dim
#define KB   64        // keys per attention step
#define SPLIT_KEYS 2048

typedef float f32x4 __attribute__((ext_vector_type(4)));
typedef short s16x8 __attribute__((ext_vector_type(8)));
typedef uint  u32x2 __attribute__((ext_vector_type(2)));

static __device__ __forceinline__ s16x8 load8(const ushort* p) {
    return *(const s16x8*)p;
}
static __device__ __forceinline__ ushort bfbits(float x) {
    __bf16 b = (__bf16)x;
    return __builtin_bit_cast(unsigned short, b);
}
static __device__ __forceinline__ float bfval(ushort u) {
    uint x = (uint)u << 16;
    return __builtin_bit_cast(float, x);
}
static __device__ __forceinline__ uint pk2(float a, float b) {
    return (uint)bfbits(a) | ((uint)bfbits(b) << 16);
}
static __device__ __forceinline__ f32x4 max4(f32x4 a, f32x4 b) {
    f32x4 r;
    r[0] = fmaxf(a[0], b[0]); r[1] = fmaxf(a[1], b[1]);
    r[2] = fmaxf(a[2], b[2]); r[3] = fmaxf(a[3], b[3]);
    return r;
}

// ---------------- input conversion ----------------

// X [256][4096] f32 -> XT hi/lo bf16 [4096][256] (transpose via LDS tiles).
__global__ __launch_bounds__(256) void convert_x_kernel(
    const float* __restrict__ x1, const float* __restrict__ x2,
    ushort* __restrict__ xt1h, ushort* __restrict__ xt1l,
    ushort* __restrict__ xt2h, ushort* __restrict__ xt2l)
{
    __shared__ float tile[64][65];
    const float* X = blockIdx.z ? x2 : x1;
    ushort* Hd = blockIdx.z ? xt2h : xt1h;
    ushort* Ld = blockIdx.z ? xt2l : xt1l;
    const int n0 = blockIdx.x * 64, c0 = blockIdx.y * 64;
    const int tj = threadIdx.x & 63, ti = threadIdx.x >> 6;
#pragma unroll
    for (int r = 0; r < 16; ++r) {
        int i = r * 4 + ti;
        tile[i][tj] = X[(c0 + i) * NPOS + n0 + tj];
    }
    __syncthreads();
#pragma unroll
    for (int r = 0; r < 16; ++r) {
        int i = r * 4 + ti;                       // n offset
        float v = tile[tj][i];                    // X[c0+tj][n0+i]
        ushort h = bfbits(v);
        ushort l = bfbits(v - bfval(h));
        Hd[(n0 + i) * NCH + c0 + tj] = h;
        Ld[(n0 + i) * NCH + c0 + tj] = l;
    }
}

// W [256][256] f32 -> hi/lo bf16, dst layout [4 matrices][2][65536].
// m=0 (Wq) gets scale folded in.
__global__ __launch_bounds__(256) void convert_w_kernel(
    const float* __restrict__ Wq, const float* __restrict__ Wk,
    const float* __restrict__ Wv, const float* __restrict__ Wp,
    ushort* __restrict__ dst, float qscale)
{
    const int m = blockIdx.y;
    const float* src = m == 0 ? Wq : m == 1 ? Wk : m == 2 ? Wv : Wp;
    const float sc = m == 0 ? qscale : 1.f;
    const int idx = (blockIdx.x * 256 + threadIdx.x) * 4;
    f32x4 w = *(const f32x4*)(src + idx);
    w *= sc;
    ushort h[4], l[4];
#pragma unroll
    for (int i = 0; i < 4; ++i) {
        h[i] = bfbits(w[i]);
        l[i] = bfbits(w[i] - bfval(h[i]));
    }
    ushort* H = dst + m * 2 * 65536;
    *(u32x2*)(H + idx)         = (u32x2){(uint)h[0] | ((uint)h[1] << 16),
                                         (uint)h[2] | ((uint)h[3] << 16)};
    *(u32x2*)(H + 65536 + idx) = (u32x2){(uint)l[0] | ((uint)l[1] << 16),
                                         (uint)l[2] | ((uint)l[3] << 16)};
}

// ---------------- bf16x3 MFMA GEMMs ----------------
// C[o][n] = sum_c W[o][c] X[c][n]; A-frag = W rows, B-frag = XT rows.
// Wave: 16 o x 32 n; block: 4 waves = 64 o x 32 n; grid (128, 4).

// Q (and K) output layout: [head][n][32] bf16.
__global__ __launch_bounds__(256) void gemm_q_kernel(
    const ushort* __restrict__ Wh, const ushort* __restrict__ Wl,
    const ushort* __restrict__ Bh, const ushort* __restrict__ Bl,
    ushort* __restrict__ Q)
{
    const int wid = threadIdx.x >> 6, lane = threadIdx.x & 63;
    const int lq = lane & 15, grp = lane >> 4;
    const int o0 = blockIdx.y * 64 + wid * 16;
    const int n0 = blockIdx.x * 32;
    const int woff = (o0 + lq) * NCH + grp * 8;
    const int boff = (n0 + lq) * NCH + grp * 8;

    f32x4 acc[2];
    acc[0] = (f32x4){0.f, 0.f, 0.f, 0.f};
    acc[1] = (f32x4){0.f, 0.f, 0.f, 0.f};
#pragma unroll
    for (int kc = 0; kc < 8; ++kc) {
        const s16x8 ah = load8(Wh + woff + kc * 32);
        const s16x8 al = load8(Wl + woff + kc * 32);
#pragma unroll
        for (int nt = 0; nt < 2; ++nt) {
            const s16x8 bh = load8(Bh + boff + nt * 16 * NCH + kc * 32);
            const s16x8 bl = load8(Bl + boff + nt * 16 * NCH + kc * 32);
            acc[nt] = __builtin_amdgcn_mfma_f32_16x16x32_bf16(ah, bh, acc[nt], 0, 0, 0);
            acc[nt] = __builtin_amdgcn_mfma_f32_16x16x32_bf16(ah, bl, acc[nt], 0, 0, 0);
            acc[nt] = __builtin_amdgcn_mfma_f32_16x16x32_bf16(al, bh, acc[nt], 0, 0, 0);
        }
    }
    const int head = o0 >> 5, d0 = (o0 & 31) + grp * 4;
#pragma unroll
    for (int nt = 0; nt < 2; ++nt) {
        const int n = n0 + nt * 16 + lq;
        *(u32x2*)(Q + head * (NPOS * HD) + n * HD + d0) =
            (u32x2){pk2(acc[nt][0], acc[nt][1]), pk2(acc[nt][2], acc[nt][3])};
    }
}

// K+V fused (shared B-frags): K -> [head][n][32], V -> [o][n].
__global__ __launch_bounds__(256) void gemm_kv_kernel(
    const ushort* __restrict__ Wkh, const ushort* __restrict__ Wkl,
    const ushort* __restrict__ Wvh, const ushort* __restrict__ Wvl,
    const ushort* __restrict__ Bh, const ushort* __restrict__ Bl,
    ushort* __restrict__ Kq, ushort* __restrict__ V)
{
    const int wid = threadIdx.x >> 6, lane = threadIdx.x & 63;
    const int lq = lane & 15, grp = lane >> 4;
    const int o0 = blockIdx.y * 64 + wid * 16;
    const int n0 = blockIdx.x * 32;
    const int woff = (o0 + lq) * NCH + grp * 8;
    const int boff = (n0 + lq) * NCH + grp * 8;

    f32x4 ka[2], va[2];
    ka[0] = (f32x4){0.f, 0.f, 0.f, 0.f}; ka[1] = ka[0];
    va[0] = ka[0]; va[1] = ka[0];
#pragma unroll
    for (int kc = 0; kc < 8; ++kc) {
        const s16x8 akh = load8(Wkh + woff + kc * 32);
        const s16x8 akl = load8(Wkl + woff + kc * 32);
        const s16x8 avh = load8(Wvh + woff + kc * 32);
        const s16x8 avl = load8(Wvl + woff + kc * 32);
#pragma unroll
        for (int nt = 0; nt < 2; ++nt) {
            const s16x8 bh = load8(Bh + boff + nt * 16 * NCH + kc * 32);
            const s16x8 bl = load8(Bl + boff + nt * 16 * NCH + kc * 32);
            ka[nt] = __builtin_amdgcn_mfma_f32_16x16x32_bf16(akh, bh, ka[nt], 0, 0, 0);
            ka[nt] = __builtin_amdgcn_mfma_f32_16x16x32_bf16(akh, bl, ka[nt], 0, 0, 0);
            ka[nt] = __builtin_amdgcn_mfma_f32_16x16x32_bf16(akl, bh, ka[nt], 0, 0, 0);
            va[nt] = __builtin_amdgcn_mfma_f32_16x16x32_bf16(avh, bh, va[nt], 0, 0, 0);
            va[nt] = __builtin_amdgcn_mfma_f32_16x16x32_bf16(avh, bl, va[nt], 0, 0, 0);
            va[nt] = __builtin_amdgcn_mfma_f32_16x16x32_bf16(avl, bh, va[nt], 0, 0, 0);
        }
    }
    const int head = o0 >> 5, d0 = (o0 & 31) + grp * 4;
#pragma unroll
    for (int nt = 0; nt < 2; ++nt) {
        const int n = n0 + nt * 16 + lq;
        *(u32x2*)(Kq + head * (NPOS * HD) + n * HD + d0) =
            (u32x2){pk2(ka[nt][0], ka[nt][1]), pk2(ka[nt][2], ka[nt][3])};
#pragma unroll
        for (int r = 0; r < 4; ++r)
            V[(o0 + grp * 4 + r) * NPOS + n] = bfbits(va[nt][r]);
    }
}

// Output projection: C = Wp @ F + bias, f32 out [256][4096].
__global__ __launch_bounds__(256) void gemm_out_kernel(
    const ushort* __restrict__ Wh, const ushort* __restrict__ Wl,
    const ushort* __restrict__ Bh, const ushort* __restrict__ Bl,
    const float* __restrict__ bias, float* __restrict__ Y)
{
    const int wid = threadIdx.x >> 6, lane = threadIdx.x & 63;
    const int lq = lane & 15, grp = lane >> 4;
    const int o0 = blockIdx.y * 64 + wid * 16;
    const int n0 = blockIdx.x * 32;
    const int woff = (o0 + lq) * NCH + grp * 8;
    const int boff = (n0 + lq) * NCH + grp * 8;

    f32x4 acc[2];
    acc[0] = (f32x4){0.f, 0.f, 0.f, 0.f};
    acc[1] = acc[0];
#pragma unroll
    for (int kc = 0; kc < 8; ++kc) {
        const s16x8 ah = load8(Wh + woff + kc * 32);
        const s16x8 al = load8(Wl + woff + kc * 32);
#pragma unroll
        for (int nt = 0; nt < 2; ++nt) {
            const s16x8 bh = load8(Bh + boff + nt * 16 * NCH + kc * 32);
            const s16x8 bl = load8(Bl + boff + nt * 16 * NCH + kc * 32);
            acc[nt] = __builtin_amdgcn_mfma_f32_16x16x32_bf16(ah, bh, acc[nt], 0, 0, 0);
            acc[nt] = __builtin_amdgcn_mfma_f32_16x16x32_bf16(ah, bl, acc[nt], 0, 0, 0);
            acc[nt] = __builtin_amdgcn_mfma_f32_16x16x32_bf16(al, bh, acc[nt], 0, 0, 0);
        }
    }
    const f32x4 b4 = *(const f32x4*)(bias + o0 + grp * 4);
#pragma unroll
    for (int nt = 0; nt < 2; ++nt) {
        const int n = n0 + nt * 16 + lq;
#pragma unroll
        for (int r = 0; r < 4; ++r)
            Y[(o0 + grp * 4 + r) * NPOS + n] = acc[nt][r] + b4[r];
    }
}

// ---------------- MFMA flash attention, split-K over 2 ----------------
__global__ __launch_bounds__(256) void attn_mfma_kernel(
    const ushort* __restrict__ Qt,   // [8][4096][32] bf16, pre-scaled s*log2e
    const ushort* __restrict__ Kt,   // [8][4096][32] bf16
    const ushort* __restrict__ Vt,   // [8][32][4096] bf16
    float* __restrict__ Op,          // [2][4096][256] f32 unnormalized (n-major!)
    float* __restrict__ Ml)          // [2][8][2][4096] f32 (m, l)
{
    __shared__ ushort pt_all[4][32 * KB];
    const int bid  = blockIdx.x;
    const int s    = bid >> 8;
    const int h    = bid & 7;
    const int qblk = (bid & 255) >> 3;   // 0..31
    const int wid  = threadIdx.x >> 6;
    const int lane = threadIdx.x & 63;
    const int lq   = lane & 15;
    const int grp  = lane >> 4;
    const int q0   = qblk * 128 + wid * 32;
    const int k0   = s * SPLIT_KEYS;

    ushort* pt = pt_all[wid];
    const int hq = h * (NPOS * HD);

    s16x8 qf[2];
#pragma unroll
    for (int qt = 0; qt < 2; ++qt)
        qf[qt] = load8(Qt + hq + (q0 + qt * 16 + lq) * HD + grp * 8);

    const ushort* kbase = Kt + hq + lq * HD + grp * 8;
    const ushort* vbase = Vt + h * (HD * NPOS) + lq * NPOS + grp * 8;

    f32x4 oacc[2][2];
#pragma unroll
    for (int qt = 0; qt < 2; ++qt)
#pragma unroll
        for (int dt = 0; dt < 2; ++dt)
            oacc[qt][dt] = (f32x4){0.f, 0.f, 0.f, 0.f};
    float m_run[2] = {-INFINITY, -INFINITY};
    float l_run[2] = {0.f, 0.f};

    s16x8 kf[4];
#pragma unroll
    for (int t = 0; t < 4; ++t) kf[t] = load8(kbase + (k0 + t * 16) * HD);

    for (int m0 = k0; m0 < k0 + SPLIT_KEYS; m0 += KB) {
        f32x4 s_[2][4];
#pragma unroll
        for (int t = 0; t < 4; ++t)
#pragma unroll
            for (int qt = 0; qt < 2; ++qt)
                s_[qt][t] = __builtin_amdgcn_mfma_f32_16x16x32_bf16(
                    kf[t], qf[qt], (f32x4){0.f, 0.f, 0.f, 0.f}, 0, 0, 0);

        const int mn = k0 + ((m0 - k0 + KB) & (SPLIT_KEYS - 1));
        s16x8 kn[4];
#pragma unroll
        for (int t = 0; t < 4; ++t) kn[t] = load8(kbase + (mn + t * 16) * HD);
        s16x8 vf[2][2];
#pragma unroll
        for (int ks = 0; ks < 2; ++ks)
#pragma unroll
            for (int dt = 0; dt < 2; ++dt)
                vf[ks][dt] = load8(vbase + dt * 16 * NPOS + m0 + ks * 32);

#pragma unroll
        for (int qt = 0; qt < 2; ++qt) {
            f32x4 mv = max4(max4(s_[qt][0], s_[qt][1]), max4(s_[qt][2], s_[qt][3]));
            float mt = fmaxf(fmaxf(mv[0], mv[1]), fmaxf(mv[2], mv[3]));
            mt = fmaxf(mt, __shfl_xor(mt, 16));
            mt = fmaxf(mt, __shfl_xor(mt, 32));
            if (__any(mt > m_run[qt] + 8.f)) {
                const float mnew  = fmaxf(m_run[qt], mt);
                const float alpha = __builtin_amdgcn_exp2f(m_run[qt] - mnew);
                m_run[qt] = mnew;
                l_run[qt] *= alpha;
                oacc[qt][0] *= alpha;
                oacc[qt][1] *= alpha;
            }
            float ls = 0.f;
#pragma unroll
            for (int t = 0; t < 4; ++t) {
                const float p0 = __builtin_amdgcn_exp2f(s_[qt][t][0] - m_run[qt]);
                const float p1 = __builtin_amdgcn_exp2f(s_[qt][t][1] - m_run[qt]);
                const float p2 = __builtin_amdgcn_exp2f(s_[qt][t][2] - m_run[qt]);
                const float p3 = __builtin_amdgcn_exp2f(s_[qt][t][3] - m_run[qt]);
                ls += (p0 + p1) + (p2 + p3);
                const int mrow = t * 16 + grp * 4;
                const int hw = (qt * 16 + lq) * KB +
                               (((mrow >> 3) ^ (lq & 7)) << 3) + (mrow & 7);
                *(uint*)(pt + hw)     = pk2(p0, p1);
                *(uint*)(pt + hw + 2) = pk2(p2, p3);
            }
            l_run[qt] += ls;
        }

#pragma unroll
        for (int ks = 0; ks < 2; ++ks)
#pragma unroll
            for (int qt = 0; qt < 2; ++qt) {
                const int hw = (qt * 16 + lq) * KB +
                               ((((ks * 32 + grp * 8) >> 3) ^ (lq & 7)) << 3);
                const s16x8 pf = *(const s16x8*)(pt + hw);
                oacc[qt][0] = __builtin_amdgcn_mfma_f32_16x16x32_bf16(
                    vf[ks][0], pf, oacc[qt][0], 0, 0, 0);
                oacc[qt][1] = __builtin_amdgcn_mfma_f32_16x16x32_bf16(
                    vf[ks][1], pf, oacc[qt][1], 0, 0, 0);
            }

#pragma unroll
        for (int t = 0; t < 4; ++t) kf[t] = kn[t];
    }

    // --- write unnormalized partials (n-major, f32x4) + (m, l) ---
    float* Ops = Op + s * (NPOS * NCH);
#pragma unroll
    for (int qt = 0; qt < 2; ++qt) {
        float l = l_run[qt];
        l += __shfl_xor(l, 16);
        l += __shfl_xor(l, 32);
        const int n = q0 + qt * 16 + lq;
#pragma unroll
        for (int dt = 0; dt < 2; ++dt)
            *(f32x4*)(Ops + n * NCH + h * HD + dt * 16 + grp * 4) = oacc[qt][dt];
        if (lane < 16) {
            Ml[((s * 8 + h) * 2) * NPOS + n]     = m_run[qt];
            Ml[((s * 8 + h) * 2 + 1) * NPOS + n] = l;
        }
    }
}

// split-K combine + hi/lo conversion: Op[2][n][c] -> FT hi/lo [n][c] bf16.
__global__ __launch_bounds__(256) void combine_kernel(
    const float* __restrict__ Op, const float* __restrict__ Ml,
    ushort* __restrict__ FH, ushort* __restrict__ FL)
{
    const int n = blockIdx.x * 4 + (threadIdx.x >> 6);
    const int c = (threadIdx.x & 63) * 4;
    const int h = c >> 5;
    const float m0 = Ml[(h * 2) * NPOS + n];
    const float l0 = Ml[(h * 2 + 1) * NPOS + n];
    const float m1 = Ml[((8 + h) * 2) * NPOS + n];
    const float l1 = Ml[((8 + h) * 2 + 1) * NPOS + n];
    const float M  = fmaxf(m0, m1);
    const float w0 = __builtin_amdgcn_exp2f(m0 - M);
    const float w1 = __builtin_amdgcn_exp2f(m1 - M);
    const float inv = 1.f / fmaf(l0, w0, l1 * w1);
    const float a0 = w0 * inv, a1 = w1 * inv;
    f32x4 v0 = *(const f32x4*)(Op + n * NCH + c);
    f32x4 v1 = *(const f32x4*)(Op + NPOS * NCH + n * NCH + c);
    ushort hb[4], lb[4];
#pragma unroll
    for (int i = 0; i < 4; ++i) {
        float f = fmaf(v0[i], a0, v1[i] * a1);
        hb[i] = bfbits(f);
        lb[i] = bfbits(f - bfval(hb[i]));
    }
    *(u32x2*)(FH + n * NCH + c) = (u32x2){(uint)hb[0] | ((uint)hb[1] << 16),
                                          (uint)hb[2] | ((uint)hb[3] << 16)};
    *(u32x2*)(FL + n * NCH + c) = (u32x2){(uint)lb[0] | ((uint)lb[1] << 16),
                                          (uint)lb[2] | ((uint)lb[3] << 16)};
}

extern "C" void kernel_launch(void* const* d_in, const int* in_sizes, int n_in,
                              void* d_out, int out_size, void* d_ws, size_t ws_size,
                              hipStream_t stream) {
    const float* x1 = (const float*)d_in[0];
    const float* x2 = (const float*)d_in[1];
    const float* Wq = (const float*)d_in[2];
    const float* Wk = (const float*)d_in[3];
    const float* Wv = (const float*)d_in[4];
    const float* Wp = (const float*)d_in[5];
    const float* bp = (const float*)d_in[6];
    float* out = (float*)d_out;

    const size_t MB = 1u << 20;
    char* wsc = (char*)d_ws;
    ushort* xt1h = (ushort*)(wsc + 0 * MB);
    ushort* xt1l = (ushort*)(wsc + 2 * MB);
    ushort* xt2h = (ushort*)(wsc + 4 * MB);
    ushort* xt2l = (ushort*)(wsc + 6 * MB);
    ushort* qt   = (ushort*)(wsc + 8 * MB);
    ushort* kt   = (ushort*)(wsc + 10 * MB);
    ushort* vt   = (ushort*)(wsc + 12 * MB);
    ushort* wsp  = (ushort*)(wsc + 14 * MB);   // [4][2][65536] bf16
    float*  Ml   = (float*)(wsc + 15 * MB);    // [2][8][2][4096]
    float*  Op   = (float*)(wsc + 0 * MB);     // [2][4096][256] (over xt*)
    ushort* fth  = (ushort*)(wsc + 8 * MB);    // over qt
    ushort* ftl  = (ushort*)(wsc + 10 * MB);   // over kt

    const float qscale = (float)(0.17677669529663687 * 1.4426950408889634);

    convert_x_kernel<<<dim3(64, 4, 2), 256, 0, stream>>>(
        x1, x2, xt1h, xt1l, xt2h, xt2l);
    convert_w_kernel<<<dim3(64, 4), 256, 0, stream>>>(
        Wq, Wk, Wv, Wp, wsp, qscale);

    ushort* wqh = wsp;            ushort* wql = wsp + 65536;
    ushort* wkh = wsp + 131072;   ushort* wkl = wsp + 196608;
    ushort* wvh = wsp + 262144;   ushort* wvl = wsp + 327680;
    ushort* wph = wsp + 393216;   ushort* wpl = wsp + 458752;

    gemm_q_kernel<<<dim3(128, 4), 256, 0, stream>>>(wqh, wql, xt1h, xt1l, qt);
    gemm_kv_kernel<<<dim3(128, 4), 256, 0, stream>>>(
        wkh, wkl, wvh, wvl, xt2h, xt2l, kt, vt);

    attn_mfma_kernel<<<512, 256, 0, stream>>>(qt, kt, vt, Op, Ml);

    combine_kernel<<<1024, 256, 0, stream>>>(Op, Ml, fth, ftl);
    gemm_out_kernel<<<dim3(128, 4), 256, 0, stream>>>(
        wph, wpl, fth, ftl, bp, out);
}